// Round 8
// baseline (105.950 us; speedup 1.0000x reference)
//
#include <hip/hip_runtime.h>

namespace {
constexpr int N   = 64;
constexpr int D   = 32;
constexpr int SHP = 404;  // sh row pad (dwords): 404%32=20 -> phase2 4-row residues
                          // {0,20,8,28} x b128 = all 32 banks, conflict-free.
                          // Sized so LDS total = 52480 B: inside the 3-blocks/CU
                          // window (40.96..53.3 KB) -> compiler VGPR target 85,
                          // avoiding the 4-blocks/CU target-64 spill trap (r4-r6).
constexpr float LOG2E = 1.4426950408889634f;
constexpr float LN2   = 0.6931471805599453f;

#if __has_builtin(__builtin_amdgcn_exp2f)
__device__ __forceinline__ float fexp2(float x) { return __builtin_amdgcn_exp2f(x); }
#else
__device__ __forceinline__ float fexp2(float x) { return exp2f(x); }
#endif
#if __has_builtin(__builtin_amdgcn_rcpf)
__device__ __forceinline__ float frcp(float x) { return __builtin_amdgcn_rcpf(x); }
#else
__device__ __forceinline__ float frcp(float x) { return 1.0f / x; }
#endif

// Grid 1024 = 2 blocks per b (32 i-rows), block 512 (8 waves).
// r7 LESSON: with spills fixed, kernel sits at ~38us = dual-pipe saturation;
// ~179 LDS insts/wave (staging+gate+score broadcasts+swizzles+phase2) is an
// LDS-pipe time comparable to VALU time. FIX: indicator is 24 KB, L1-resident
// -> read all broadcast/uniform operands from GLOBAL (VMEM pipe) and delete
// ind_lds. LDS keeps only s (3x64) and sh (the j-transpose round-trip).
// Gate: __ballot bitmask per row (SGPR, zero VGPR/LDS across score loop).
// Single-exp identity (exact):
//   elup1(a)*elup1(b) = exp2(min(aL,0)+min(bL,0)) * (1+max(aL,0)*ln2) * (1+max(bL,0)*ln2)
__global__ __launch_bounds__(512, 4) void fused(
        const float* __restrict__ feature,
        const float* __restrict__ ind,
        float* __restrict__ out) {
    __shared__ float s_lds[3][N];         //   768 B
    __shared__ float sh_lds[32][SHP];     // 51712 B   total 52480 B -> 3 blocks/CU

    const int t      = threadIdx.x;
    const int lane   = t & 63;
    const int wave   = t >> 6;
    const int blk    = blockIdx.x;
    const int b      = blk >> 1;
    const int i_base = (blk & 1) << 5;

    const float4* ind0_4 = reinterpret_cast<const float4*>(ind);              // [N][8]
    const float4* ind1_4 = reinterpret_cast<const float4*>(ind + N * D);      // [N][8]
    const float4* ind2_4 = reinterpret_cast<const float4*>(ind + 2 * N * D);  // [N][8]

    // ---- u = ind0[lane,:] in 32 VGPRs (global, L1-hot) ----
    float4 u[8];
#pragma unroll
    for (int k = 0; k < 8; ++k) u[k] = ind0_4[lane * 8 + k];

    // ---- gate bitmasks for this wave's 4 rows: 1[ ind0[ig,:] . ind1[lane,:] > 0 ] ----
    unsigned long long gmask[4];
    {
        float ga[4] = {0.f, 0.f, 0.f, 0.f};
#pragma unroll
        for (int k = 0; k < 8; ++k) {
            float4 w4 = ind1_4[lane * 8 + k];                       // per-lane (VMEM)
#pragma unroll
            for (int r = 0; r < 4; ++r) {
                float4 a4 = ind0_4[(i_base + wave * 4 + r) * 8 + k];  // broadcast (VMEM)
                ga[r] += a4.x * w4.x + a4.y * w4.y + a4.z * w4.z + a4.w * w4.w;
            }
        }
#pragma unroll
        for (int r = 0; r < 4; ++r) gmask[r] = __ballot(ga[r] > 0.f);
    }

    // ---- s[a][n] = feature[b,n,:] . ind[a,n,:]  (threads < 192, global reads) ----
    if (t < 3 * N) {
        int a = t >> 6, n = t & 63;
        const float4* frow = reinterpret_cast<const float4*>(feature + ((size_t)b * N + n) * D);
        const float4* irow = reinterpret_cast<const float4*>(ind + (a * N + n) * D);
        float sa = 0.f;
#pragma unroll
        for (int k = 0; k < 8; ++k) {
            float4 f4 = frow[k];
            float4 i4 = irow[k];
            sa += f4.x * i4.x + f4.y * i4.y + f4.z * i4.z + f4.w * i4.w;
        }
        s_lds[a][n] = sa;
    }
    __syncthreads();

    const float s1L = s_lds[1][lane] * LOG2E;

    // ---- score: wave rows ig = i_base + wave*4 + r; v-rows from global (VMEM bcast) ----
    float score[4];
#pragma unroll
    for (int r = 0; r < 4; ++r) {
        const int   ig  = i_base + wave * 4 + r;
        const float s0L = s_lds[0][ig] * LOG2E;
        float sc = 0.f;
#pragma unroll
        for (int k = 0; k < 8; ++k) {
            float4 v4 = ind1_4[ig * 8 + k];                         // broadcast (VMEM)
#pragma unroll
            for (int c = 0; c < 4; ++c) {
                float aL = s0L * (&u[k].x)[c];
                float bL = s1L * (&v4.x)[c];
                float E  = fexp2(fminf(aL, 0.f) + fminf(bL, 0.f));
                float A  = fmaf(fmaxf(aL, 0.f), LN2, 1.0f);
                float B  = fmaf(fmaxf(bL, 0.f), LN2, 1.0f);
                sc = fmaf(E * A, B, sc);
            }
        }
        score[r] = sc;
    }

    // ---- 4-way-ILP wave softmax over j (64 lanes) ----
    float mx[4], e[4], sm[4];
#pragma unroll
    for (int r = 0; r < 4; ++r) mx[r] = score[r];
#pragma unroll
    for (int off = 32; off >= 1; off >>= 1) {
#pragma unroll
        for (int r = 0; r < 4; ++r) mx[r] = fmaxf(mx[r], __shfl_xor(mx[r], off));
    }
#pragma unroll
    for (int r = 0; r < 4; ++r) e[r] = fexp2((score[r] - mx[r]) * LOG2E);
#pragma unroll
    for (int r = 0; r < 4; ++r) sm[r] = e[r];
#pragma unroll
    for (int off = 32; off >= 1; off >>= 1) {
#pragma unroll
        for (int r = 0; r < 4; ++r) sm[r] += __shfl_xor(sm[r], off);
    }
#pragma unroll
    for (int r = 0; r < 4; ++r) {
        const int ig    = i_base + wave * 4 + r;
        const int i_loc = wave * 4 + r;
        const float g   = (float)((gmask[r] >> lane) & 1ull);
        sh_lds[i_loc][lane] = (e[r] * g) * (s_lds[2][ig] * frcp(sm[r]));
    }
    __syncthreads();

    // ---- phase 2: out[i,:] = sh[i,:] @ ind2; thread = (i_loc, d-quad, j-half);
    //      ind2 from global (VMEM, L1-hot), sh from LDS ----
    {
        const int i_loc = t >> 4;
        const int sub   = t & 15;
        const int dq    = sub & 7;
        const int jh    = sub >> 3;
        float4 acc = {0.f, 0.f, 0.f, 0.f};
#pragma unroll
        for (int jj = 0; jj < 32; jj += 4) {
            int j = jh * 32 + jj;
            float4 sh4 = *reinterpret_cast<const float4*>(&sh_lds[i_loc][j]);
#pragma unroll
            for (int c = 0; c < 4; ++c) {
                float4 v4 = ind2_4[(j + c) * 8 + dq];
                float  w  = (&sh4.x)[c];
                acc.x = fmaf(w, v4.x, acc.x);
                acc.y = fmaf(w, v4.y, acc.y);
                acc.z = fmaf(w, v4.z, acc.z);
                acc.w = fmaf(w, v4.w, acc.w);
            }
        }
        acc.x += __shfl_xor(acc.x, 8);   // combine j-halves (lanes t, t^8)
        acc.y += __shfl_xor(acc.y, 8);
        acc.z += __shfl_xor(acc.z, 8);
        acc.w += __shfl_xor(acc.w, 8);
        if (jh == 0) {
            *reinterpret_cast<float4*>(out + ((size_t)b * N + i_base + i_loc) * D + dq * 4) = acc;
        }
    }
}
}  // namespace

extern "C" void kernel_launch(void* const* d_in, const int* in_sizes, int n_in,
                              void* d_out, int out_size, void* d_ws, size_t ws_size,
                              hipStream_t stream) {
    const float* feature = (const float*)d_in[0];
    const float* ind     = (const float*)d_in[1];
    float*       out     = (float*)d_out;
    fused<<<1024, 512, 0, stream>>>(feature, ind, out);
}

// Round 9
// 90.175 us; speedup vs baseline: 1.1749x; 1.1749x over previous
//
#include <hip/hip_runtime.h>

namespace {
constexpr int N   = 64;
constexpr int D   = 32;
constexpr int PD  = 36;  // padded ind row (dwords): measured conflict-free (r1/r2)
constexpr int SHP = 68;  // sh row pad: phase2 rows hit banks 4i..4i+3, conflict-free
constexpr float LOG2E = 1.4426950408889634f;
constexpr float LN2   = 0.6931471805599453f;

#if __has_builtin(__builtin_amdgcn_exp2f)
__device__ __forceinline__ float fexp2(float x) { return __builtin_amdgcn_exp2f(x); }
#else
__device__ __forceinline__ float fexp2(float x) { return exp2f(x); }
#endif
#if __has_builtin(__builtin_amdgcn_rcpf)
__device__ __forceinline__ float frcp(float x) { return __builtin_amdgcn_rcpf(x); }
#else
__device__ __forceinline__ float frcp(float x) { return 1.0f / x; }
#endif

// Grid 512 = ONE block per b (64 i-rows), block 512 (8 waves), wave owns 8 rows.
// 2 blocks/CU, all 512 blocks co-resident in one batch -> ZERO tail (r7's grid
// 1024 left a 256-block tail at 3-blocks/CU capacity).
// r8 LESSON: broadcast operands from global (VMEM) regressed 38->57us on
// latency exposure; LDS broadcasts are the cheaper carrier. ind stays in LDS.
// LDS total 45824 B: inside the 3-blocks/CU compiler window (41..53.3 KB) ->
// VGPR target 85 (r4-r6 spill trap was the <=40.96 KB window's target 64).
// Gate: __ballot bitmasks (SGPRs). Single-exp identity (exact):
//   elup1(a)*elup1(b) = exp2(min(aL,0)+min(bL,0)) * (1+max(aL,0)*ln2) * (1+max(bL,0)*ln2)
__global__ __launch_bounds__(512, 4) void fused(
        const float* __restrict__ feature,
        const float* __restrict__ ind,
        float* __restrict__ out) {
    __shared__ float ind_lds[3][N][PD];   // 27648 B
    __shared__ float s_lds[3][N];         //   768 B
    __shared__ float sh_lds[N][SHP];      // 17408 B   total 45824 B

    const int t    = threadIdx.x;
    const int lane = t & 63;
    const int wave = t >> 6;
    const int b    = blockIdx.x;

    // ---- stage indicator: 1536 float4, 3 per thread, coalesced ----
    {
        const float4* src = reinterpret_cast<const float4*>(ind);
#pragma unroll
        for (int idx = t; idx < 3 * N * D / 4; idx += 512) {
            int a = idx >> 9;
            int r = idx & 511;
            int n = r >> 3;
            int k = r & 7;
            *reinterpret_cast<float4*>(&ind_lds[a][n][k * 4]) = src[idx];
        }
    }
    __syncthreads();

    // ---- gate bitmasks for this wave's 8 rows (SGPR-resident) ----
    // gate[ig][lane] = 1[ ind0[ig,:] . ind1[lane,:] > 0 ]
    unsigned long long gmask[8];
    {
        float ga[8] = {0.f, 0.f, 0.f, 0.f, 0.f, 0.f, 0.f, 0.f};
#pragma unroll
        for (int k = 0; k < 8; ++k) {
            float4 w4 = *reinterpret_cast<const float4*>(&ind_lds[1][lane][k * 4]);  // lane read
#pragma unroll
            for (int r = 0; r < 8; ++r) {
                float4 a4 = *reinterpret_cast<const float4*>(
                    &ind_lds[0][wave * 8 + r][k * 4]);                               // broadcast
                ga[r] += a4.x * w4.x + a4.y * w4.y + a4.z * w4.z + a4.w * w4.w;
            }
        }
#pragma unroll
        for (int r = 0; r < 8; ++r) gmask[r] = __ballot(ga[r] > 0.f);
    }

    // ---- s[a][n] = feature[b,n,:] . ind[a,n,:]  (threads < 192) ----
    if (t < 3 * N) {
        int a = t >> 6, n = t & 63;
        const float4* frow = reinterpret_cast<const float4*>(feature + ((size_t)b * N + n) * D);
        float sa = 0.f;
#pragma unroll
        for (int k = 0; k < 8; ++k) {
            float4 f4 = frow[k];
            float4 i4 = *reinterpret_cast<const float4*>(&ind_lds[a][n][k * 4]);
            sa += f4.x * i4.x + f4.y * i4.y + f4.z * i4.z + f4.w * i4.w;
        }
        s_lds[a][n] = sa;
    }
    __syncthreads();

    // ---- per-lane: u = ind0[lane,:] in 32 VGPRs; s1 pre-scaled ----
    float4 u[8];
#pragma unroll
    for (int k = 0; k < 8; ++k)
        u[k] = *reinterpret_cast<const float4*>(&ind_lds[0][lane][k * 4]);
    const float s1L = s_lds[1][lane] * LOG2E;

    // ---- score + softmax: 2 groups of 4 rows (ILP in softmax trees) ----
#pragma unroll 1
    for (int g = 0; g < 2; ++g) {
        const int i0 = wave * 8 + g * 4;
        float score[4];
#pragma unroll
        for (int r = 0; r < 4; ++r) {
            const int   ig  = i0 + r;
            const float s0L = s_lds[0][ig] * LOG2E;
            float sc = 0.f;
#pragma unroll
            for (int k = 0; k < 8; ++k) {
                float4 v4 = *reinterpret_cast<const float4*>(&ind_lds[1][ig][k * 4]);  // bcast
#pragma unroll
                for (int c = 0; c < 4; ++c) {
                    float aL = s0L * (&u[k].x)[c];
                    float bL = s1L * (&v4.x)[c];
                    float E  = fexp2(fminf(aL, 0.f) + fminf(bL, 0.f));
                    float A  = fmaf(fmaxf(aL, 0.f), LN2, 1.0f);
                    float B  = fmaf(fmaxf(bL, 0.f), LN2, 1.0f);
                    sc = fmaf(E * A, B, sc);
                }
            }
            score[r] = sc;
        }

        float mx[4], e[4], sm[4];
#pragma unroll
        for (int r = 0; r < 4; ++r) mx[r] = score[r];
#pragma unroll
        for (int off = 32; off >= 1; off >>= 1) {
#pragma unroll
            for (int r = 0; r < 4; ++r) mx[r] = fmaxf(mx[r], __shfl_xor(mx[r], off));
        }
#pragma unroll
        for (int r = 0; r < 4; ++r) e[r] = fexp2((score[r] - mx[r]) * LOG2E);
#pragma unroll
        for (int r = 0; r < 4; ++r) sm[r] = e[r];
#pragma unroll
        for (int off = 32; off >= 1; off >>= 1) {
#pragma unroll
            for (int r = 0; r < 4; ++r) sm[r] += __shfl_xor(sm[r], off);
        }
#pragma unroll
        for (int r = 0; r < 4; ++r) {
            const int ig  = i0 + r;
            const float gt = (float)((gmask[g * 4 + r] >> lane) & 1ull);
            sh_lds[ig][lane] = (e[r] * gt) * (s_lds[2][ig] * frcp(sm[r]));
        }
    }
    __syncthreads();

    // ---- phase 2: out[i,:] = sh[i,:] @ ind2; thread = (i, d-quad), full 64-j dot.
    //      sh rows: bank 4i..4i+3 across 8 i's -> all 32 banks, conflict-free;
    //      ind2 reads: 8 distinct dq addresses x 8-way broadcast, conflict-free. ----
    {
        const int i  = t >> 3;
        const int dq = t & 7;
        float4 acc = {0.f, 0.f, 0.f, 0.f};
#pragma unroll 4
        for (int j = 0; j < N; j += 4) {
            float4 sh4 = *reinterpret_cast<const float4*>(&sh_lds[i][j]);
#pragma unroll
            for (int c = 0; c < 4; ++c) {
                float4 v4 = *reinterpret_cast<const float4*>(&ind_lds[2][j + c][dq * 4]);
                float  w  = (&sh4.x)[c];
                acc.x = fmaf(w, v4.x, acc.x);
                acc.y = fmaf(w, v4.y, acc.y);
                acc.z = fmaf(w, v4.z, acc.z);
                acc.w = fmaf(w, v4.w, acc.w);
            }
        }
        *reinterpret_cast<float4*>(out + ((size_t)b * N + i) * D + dq * 4) = acc;
    }
}
}  // namespace

extern "C" void kernel_launch(void* const* d_in, const int* in_sizes, int n_in,
                              void* d_out, int out_size, void* d_ws, size_t ws_size,
                              hipStream_t stream) {
    const float* feature = (const float*)d_in[0];
    const float* ind     = (const float*)d_in[1];
    float*       out     = (float*)d_out;
    fused<<<512, 512, 0, stream>>>(feature, ind, out);
}

// Round 11
// 87.496 us; speedup vs baseline: 1.2109x; 1.0306x over previous
//
#include <hip/hip_runtime.h>

namespace {
constexpr int N   = 64;
constexpr int D   = 32;
constexpr int PD  = 36;  // padded ind row (dwords): measured conflict-free (r1/r2)
constexpr int SHP = 72;  // sh row pad (dwords): MUST be >= 64 (row payload is 64
                         // lanes — r10's SHP=48 overflowed rows -> absmax 65.5).
                         // 72%32=8: softmax writes 2-way (free); phase2 b128 reads
                         // have 4 i_loc bank-offsets {0,8,16,24} x 2 jh same-bank
                         // -> 2-way (free). LDS total 37632 B <= 40960 -> 4 blocks/CU.
constexpr float LOG2E = 1.4426950408889634f;
constexpr float LN2   = 0.6931471805599453f;

#if __has_builtin(__builtin_amdgcn_exp2f)
__device__ __forceinline__ float fexp2(float x) { return __builtin_amdgcn_exp2f(x); }
#else
__device__ __forceinline__ float fexp2(float x) { return exp2f(x); }
#endif
#if __has_builtin(__builtin_amdgcn_rcpf)
__device__ __forceinline__ float frcp(float x) { return __builtin_amdgcn_rcpf(x); }
#else
__device__ __forceinline__ float frcp(float x) { return 1.0f / x; }
#endif

// Grid 1024 = 2 blocks per b (32 i-rows each), block 512 (8 waves).
// LDS 37632 B -> 4 blocks/CU; grid 1024 = exactly 256 CU x 4 -> one full batch,
// zero tail AND 8 waves/EU (r7 ran 6 waves/EU at 53.5 KB; r9 showed occupancy
// beats tail-smoothing). ALLOCATOR MODEL TEST: 4-blocks/CU implies VGPR target
// 64; r7's natural pressure was exactly 64, so no spill expected (r4-r6 spilled
// only because natural pressure exceeded the target).
// Gate: __ballot bitmasks (SGPRs). Single-exp identity (exact):
//   elup1(a)*elup1(b) = exp2(min(aL,0)+min(bL,0)) * (1+max(aL,0)*ln2) * (1+max(bL,0)*ln2)
__global__ __launch_bounds__(512, 4) void fused(
        const float* __restrict__ feature,
        const float* __restrict__ ind,
        float* __restrict__ out) {
    __shared__ float ind_lds[3][N][PD];   // 27648 B
    __shared__ float s_lds[3][N];         //   768 B
    __shared__ float sh_lds[32][SHP];     //  9216 B   total 37632 B -> 4 blocks/CU

    const int t      = threadIdx.x;
    const int lane   = t & 63;
    const int wave   = t >> 6;
    const int blk    = blockIdx.x;
    const int b      = blk >> 1;
    const int i_base = (blk & 1) << 5;

    // ---- stage indicator: 1536 float4, 3 per thread, coalesced ----
    {
        const float4* src = reinterpret_cast<const float4*>(ind);
#pragma unroll
        for (int idx = t; idx < 3 * N * D / 4; idx += 512) {
            int a = idx >> 9;
            int r = idx & 511;
            int n = r >> 3;
            int k = r & 7;
            *reinterpret_cast<float4*>(&ind_lds[a][n][k * 4]) = src[idx];
        }
    }
    __syncthreads();

    // ---- gate bitmasks for this wave's 4 rows (SGPR-resident, ~0 pressure) ----
    // gate[ig][lane] = 1[ ind0[ig,:] . ind1[lane,:] > 0 ]
    unsigned long long gmask[4];
    {
        float ga[4] = {0.f, 0.f, 0.f, 0.f};
#pragma unroll
        for (int k = 0; k < 8; ++k) {
            float4 w4 = *reinterpret_cast<const float4*>(&ind_lds[1][lane][k * 4]);  // lane read
#pragma unroll
            for (int r = 0; r < 4; ++r) {
                float4 a4 = *reinterpret_cast<const float4*>(
                    &ind_lds[0][i_base + wave * 4 + r][k * 4]);                      // broadcast
                ga[r] += a4.x * w4.x + a4.y * w4.y + a4.z * w4.z + a4.w * w4.w;
            }
        }
#pragma unroll
        for (int r = 0; r < 4; ++r) gmask[r] = __ballot(ga[r] > 0.f);
    }

    // ---- s[a][n] = feature[b,n,:] . ind[a,n,:]  (threads < 192) ----
    if (t < 3 * N) {
        int a = t >> 6, n = t & 63;
        const float4* frow = reinterpret_cast<const float4*>(feature + ((size_t)b * N + n) * D);
        float sa = 0.f;
#pragma unroll
        for (int k = 0; k < 8; ++k) {
            float4 f4 = frow[k];
            float4 i4 = *reinterpret_cast<const float4*>(&ind_lds[a][n][k * 4]);
            sa += f4.x * i4.x + f4.y * i4.y + f4.z * i4.z + f4.w * i4.w;
        }
        s_lds[a][n] = sa;
    }
    __syncthreads();

    // ---- per-lane: u = ind0[lane,:] in 32 VGPRs; s1 pre-scaled ----
    float4 u[8];
#pragma unroll
    for (int k = 0; k < 8; ++k)
        u[k] = *reinterpret_cast<const float4*>(&ind_lds[0][lane][k * 4]);
    const float s1L = s_lds[1][lane] * LOG2E;

    // ---- score: wave rows ig = i_base + wave*4 + r ----
    float score[4];
#pragma unroll
    for (int r = 0; r < 4; ++r) {
        const int   ig  = i_base + wave * 4 + r;
        const float s0L = s_lds[0][ig] * LOG2E;
        float sc = 0.f;
#pragma unroll
        for (int k = 0; k < 8; ++k) {
            float4 v4 = *reinterpret_cast<const float4*>(&ind_lds[1][ig][k * 4]);  // broadcast
#pragma unroll
            for (int c = 0; c < 4; ++c) {
                float aL = s0L * (&u[k].x)[c];
                float bL = s1L * (&v4.x)[c];
                float E  = fexp2(fminf(aL, 0.f) + fminf(bL, 0.f));
                float A  = fmaf(fmaxf(aL, 0.f), LN2, 1.0f);
                float B  = fmaf(fmaxf(bL, 0.f), LN2, 1.0f);
                sc = fmaf(E * A, B, sc);
            }
        }
        score[r] = sc;
    }

    // ---- 4-way-ILP wave softmax over j (64 lanes) ----
    float mx[4], e[4], sm[4];
#pragma unroll
    for (int r = 0; r < 4; ++r) mx[r] = score[r];
#pragma unroll
    for (int off = 32; off >= 1; off >>= 1) {
#pragma unroll
        for (int r = 0; r < 4; ++r) mx[r] = fmaxf(mx[r], __shfl_xor(mx[r], off));
    }
#pragma unroll
    for (int r = 0; r < 4; ++r) e[r] = fexp2((score[r] - mx[r]) * LOG2E);
#pragma unroll
    for (int r = 0; r < 4; ++r) sm[r] = e[r];
#pragma unroll
    for (int off = 32; off >= 1; off >>= 1) {
#pragma unroll
        for (int r = 0; r < 4; ++r) sm[r] += __shfl_xor(sm[r], off);
    }
#pragma unroll
    for (int r = 0; r < 4; ++r) {
        const int ig    = i_base + wave * 4 + r;
        const int i_loc = wave * 4 + r;
        const float g   = (float)((gmask[r] >> lane) & 1ull);
        sh_lds[i_loc][lane] = (e[r] * g) * (s_lds[2][ig] * frcp(sm[r]));
    }
    __syncthreads();

    // ---- phase 2: out[i,:] = sh[i,:] @ ind2; thread = (i_loc, d-quad, j-half) ----
    {
        const int i_loc = t >> 4;
        const int sub   = t & 15;
        const int dq    = sub & 7;
        const int jh    = sub >> 3;
        float4 acc = {0.f, 0.f, 0.f, 0.f};
#pragma unroll
        for (int jj = 0; jj < 32; jj += 4) {
            int j = jh * 32 + jj;
            float4 sh4 = *reinterpret_cast<const float4*>(&sh_lds[i_loc][j]);
#pragma unroll
            for (int c = 0; c < 4; ++c) {
                float4 v4 = *reinterpret_cast<const float4*>(&ind_lds[2][j + c][dq * 4]);
                float  w  = (&sh4.x)[c];
                acc.x = fmaf(w, v4.x, acc.x);
                acc.y = fmaf(w, v4.y, acc.y);
                acc.z = fmaf(w, v4.z, acc.z);
                acc.w = fmaf(w, v4.w, acc.w);
            }
        }
        acc.x += __shfl_xor(acc.x, 8);   // combine j-halves (lanes t, t^8)
        acc.y += __shfl_xor(acc.y, 8);
        acc.z += __shfl_xor(acc.z, 8);
        acc.w += __shfl_xor(acc.w, 8);
        if (jh == 0) {
            *reinterpret_cast<float4*>(out + ((size_t)b * N + i_base + i_loc) * D + dq * 4) = acc;
        }
    }
}
}  // namespace

extern "C" void kernel_launch(void* const* d_in, const int* in_sizes, int n_in,
                              void* d_out, int out_size, void* d_ws, size_t ws_size,
                              hipStream_t stream) {
    const float* feature = (const float*)d_in[0];
    const float* ind     = (const float*)d_in[1];
    float*       out     = (float*)d_out;
    fused<<<1024, 512, 0, stream>>>(feature, ind, out);
}

// Round 12
// 84.305 us; speedup vs baseline: 1.2567x; 1.0378x over previous
//
#include <hip/hip_runtime.h>

namespace {
constexpr int N   = 64;
constexpr int D   = 32;
constexpr int PD  = 36;   // padded ind row (dwords): measured conflict-free (r1/r2)
constexpr int SHP = 104;  // sh row pad: >=64 payload (r10 lesson), 104%32==8 ->
                          // same conflict-free banks as r11's 72. Sized UP so
                          // LDS = 41728 B > 40960 -> 3-blocks/CU window ->
                          // compiler VGPR target 85 (not 64): headroom for the
                          // packed-loop temporaries without the r4-r6 spill trap.
                          // r7 vs r11 measured 6-vs-8 waves/EU as ~0.5us - cheap.
constexpr float LOG2E = 1.4426950408889634f;
constexpr float LN2   = 0.6931471805599453f;

typedef float f32x2 __attribute__((ext_vector_type(2)));

#if __has_builtin(__builtin_amdgcn_exp2f)
__device__ __forceinline__ float fexp2(float x) { return __builtin_amdgcn_exp2f(x); }
#else
__device__ __forceinline__ float fexp2(float x) { return exp2f(x); }
#endif
#if __has_builtin(__builtin_amdgcn_rcpf)
__device__ __forceinline__ float frcp(float x) { return __builtin_amdgcn_rcpf(x); }
#else
__device__ __forceinline__ float frcp(float x) { return 1.0f / x; }
#endif

// Grid 1024 = 2 blocks per b (32 i-rows each), block 512 (8 waves).
// SCORE LOOP IS PACKED-FP32: <2 x float> mul/fma lower to v_pk_{mul,fma}_f32
// (dual-issue FP32 - the 157 TF rate); min/max/exp stay scalar-rate. Static
// model: 60 -> 46 issue-cyc per element pair, score VALU -23%.
// Evidence base: r2/r7/r11 all ~37.5us across 16/24/32 waves/CU and 1-vs-2
// exps -> issue-bound, so issue-slot reduction is the only remaining lever.
// Gate: __ballot bitmasks (SGPRs). Single-exp identity (exact):
//   elup1(a)*elup1(b) = exp2(min(aL,0)+min(bL,0)) * (1+max(aL,0)*ln2) * (1+max(bL,0)*ln2)
__global__ __launch_bounds__(512, 4) void fused(
        const float* __restrict__ feature,
        const float* __restrict__ ind,
        float* __restrict__ out) {
    __shared__ float ind_lds[3][N][PD];   // 27648 B
    __shared__ float s_lds[3][N];         //   768 B
    __shared__ float sh_lds[32][SHP];     // 13312 B   total 41728 B -> 3 blocks/CU

    const int t      = threadIdx.x;
    const int lane   = t & 63;
    const int wave   = t >> 6;
    const int blk    = blockIdx.x;
    const int b      = blk >> 1;
    const int i_base = (blk & 1) << 5;

    // ---- stage indicator: 1536 float4, 3 per thread, coalesced ----
    {
        const float4* src = reinterpret_cast<const float4*>(ind);
#pragma unroll
        for (int idx = t; idx < 3 * N * D / 4; idx += 512) {
            int a = idx >> 9;
            int r = idx & 511;
            int n = r >> 3;
            int k = r & 7;
            *reinterpret_cast<float4*>(&ind_lds[a][n][k * 4]) = src[idx];
        }
    }
    __syncthreads();

    // ---- gate bitmasks for this wave's 4 rows (SGPR-resident) ----
    // gate[ig][lane] = 1[ ind0[ig,:] . ind1[lane,:] > 0 ]
    unsigned long long gmask[4];
    {
        float ga[4] = {0.f, 0.f, 0.f, 0.f};
#pragma unroll
        for (int k = 0; k < 8; ++k) {
            float4 w4 = *reinterpret_cast<const float4*>(&ind_lds[1][lane][k * 4]);  // lane read
#pragma unroll
            for (int r = 0; r < 4; ++r) {
                float4 a4 = *reinterpret_cast<const float4*>(
                    &ind_lds[0][i_base + wave * 4 + r][k * 4]);                      // broadcast
                ga[r] += a4.x * w4.x + a4.y * w4.y + a4.z * w4.z + a4.w * w4.w;
            }
        }
#pragma unroll
        for (int r = 0; r < 4; ++r) gmask[r] = __ballot(ga[r] > 0.f);
    }

    // ---- s[a][n] = feature[b,n,:] . ind[a,n,:]  (threads < 192) ----
    if (t < 3 * N) {
        int a = t >> 6, n = t & 63;
        const float4* frow = reinterpret_cast<const float4*>(feature + ((size_t)b * N + n) * D);
        float sa = 0.f;
#pragma unroll
        for (int k = 0; k < 8; ++k) {
            float4 f4 = frow[k];
            float4 i4 = *reinterpret_cast<const float4*>(&ind_lds[a][n][k * 4]);
            sa += f4.x * i4.x + f4.y * i4.y + f4.z * i4.z + f4.w * i4.w;
        }
        s_lds[a][n] = sa;
    }
    __syncthreads();

    // ---- per-lane: u = ind0[lane,:] in 32 VGPRs (as f32x2 pairs); s1 scaled ----
    f32x2 u2[16];
#pragma unroll
    for (int k = 0; k < 8; ++k) {
        float4 v = *reinterpret_cast<const float4*>(&ind_lds[0][lane][k * 4]);
        u2[2 * k + 0] = f32x2{v.x, v.y};
        u2[2 * k + 1] = f32x2{v.z, v.w};
    }
    const float s1Ls = s_lds[1][lane] * LOG2E;
    const f32x2 s1L  = {s1Ls, s1Ls};
    const f32x2 ln2v = {LN2, LN2};
    const f32x2 onev = {1.0f, 1.0f};
    const f32x2 zerv = {0.0f, 0.0f};

    // ---- score: wave rows ig = i_base + wave*4 + r; packed-fp32 inner loop ----
    float score[4];
#pragma unroll
    for (int r = 0; r < 4; ++r) {
        const int   ig   = i_base + wave * 4 + r;
        const float s0Ls = s_lds[0][ig] * LOG2E;
        const f32x2 s0L  = {s0Ls, s0Ls};
        f32x2 sc2 = {0.f, 0.f};
#pragma unroll
        for (int k = 0; k < 8; ++k) {
            float4 v4 = *reinterpret_cast<const float4*>(&ind_lds[1][ig][k * 4]);  // broadcast
            f32x2 vp[2] = {f32x2{v4.x, v4.y}, f32x2{v4.z, v4.w}};
#pragma unroll
            for (int h = 0; h < 2; ++h) {
                f32x2 aL  = s0L * u2[2 * k + h];                       // v_pk_mul
                f32x2 bL  = s1L * vp[h];                               // v_pk_mul
                f32x2 mnS = __builtin_elementwise_min(aL, zerv)
                          + __builtin_elementwise_min(bL, zerv);       // 2 v_min + pk_add
                f32x2 E   = {fexp2(mnS.x), fexp2(mnS.y)};              // 2 v_exp
                f32x2 A   = __builtin_elementwise_fma(
                    __builtin_elementwise_max(aL, zerv), ln2v, onev);  // v_max x2 + pk_fma
                f32x2 Bv  = __builtin_elementwise_fma(
                    __builtin_elementwise_max(bL, zerv), ln2v, onev);  // v_max x2 + pk_fma
                sc2 = __builtin_elementwise_fma(E * A, Bv, sc2);       // pk_mul + pk_fma
            }
        }
        score[r] = sc2.x + sc2.y;
    }

    // ---- 4-way-ILP wave softmax over j (64 lanes) ----
    float mx[4], e[4], sm[4];
#pragma unroll
    for (int r = 0; r < 4; ++r) mx[r] = score[r];
#pragma unroll
    for (int off = 32; off >= 1; off >>= 1) {
#pragma unroll
        for (int r = 0; r < 4; ++r) mx[r] = fmaxf(mx[r], __shfl_xor(mx[r], off));
    }
#pragma unroll
    for (int r = 0; r < 4; ++r) e[r] = fexp2((score[r] - mx[r]) * LOG2E);
#pragma unroll
    for (int r = 0; r < 4; ++r) sm[r] = e[r];
#pragma unroll
    for (int off = 32; off >= 1; off >>= 1) {
#pragma unroll
        for (int r = 0; r < 4; ++r) sm[r] += __shfl_xor(sm[r], off);
    }
#pragma unroll
    for (int r = 0; r < 4; ++r) {
        const int ig    = i_base + wave * 4 + r;
        const int i_loc = wave * 4 + r;
        const float g   = (float)((gmask[r] >> lane) & 1ull);
        sh_lds[i_loc][lane] = (e[r] * g) * (s_lds[2][ig] * frcp(sm[r]));
    }
    __syncthreads();

    // ---- phase 2: out[i,:] = sh[i,:] @ ind2; thread = (i_loc, d-quad, j-half) ----
    {
        const int i_loc = t >> 4;
        const int sub   = t & 15;
        const int dq    = sub & 7;
        const int jh    = sub >> 3;
        float4 acc = {0.f, 0.f, 0.f, 0.f};
#pragma unroll
        for (int jj = 0; jj < 32; jj += 4) {
            int j = jh * 32 + jj;
            float4 sh4 = *reinterpret_cast<const float4*>(&sh_lds[i_loc][j]);
#pragma unroll
            for (int c = 0; c < 4; ++c) {
                float4 v4 = *reinterpret_cast<const float4*>(&ind_lds[2][j + c][dq * 4]);
                float  w  = (&sh4.x)[c];
                acc.x = fmaf(w, v4.x, acc.x);
                acc.y = fmaf(w, v4.y, acc.y);
                acc.z = fmaf(w, v4.z, acc.z);
                acc.w = fmaf(w, v4.w, acc.w);
            }
        }
        acc.x += __shfl_xor(acc.x, 8);   // combine j-halves (lanes t, t^8)
        acc.y += __shfl_xor(acc.y, 8);
        acc.z += __shfl_xor(acc.z, 8);
        acc.w += __shfl_xor(acc.w, 8);
        if (jh == 0) {
            *reinterpret_cast<float4*>(out + ((size_t)b * N + i_base + i_loc) * D + dq * 4) = acc;
        }
    }
}
}  // namespace

extern "C" void kernel_launch(void* const* d_in, const int* in_sizes, int n_in,
                              void* d_out, int out_size, void* d_ws, size_t ws_size,
                              hipStream_t stream) {
    const float* feature = (const float*)d_in[0];
    const float* ind     = (const float*)d_in[1];
    float*       out     = (float*)d_out;
    fused<<<1024, 512, 0, stream>>>(feature, ind, out);
}

// Round 13
// 82.128 us; speedup vs baseline: 1.2901x; 1.0265x over previous
//
#include <hip/hip_runtime.h>

namespace {
constexpr int N   = 64;
constexpr int D   = 32;
constexpr int PD  = 36;   // padded ind row (dwords): measured conflict-free (r1/r2)
constexpr int SHP = 104;  // sh row pad: >=64 payload (r10 lesson); 104%32==8
                          // conflict-free (r11/r12). LDS 41728 B -> 3-blocks/CU
                          // window -> compiler VGPR target 85 (r4-r6 spill trap
                          // fires in the <=40.96 KB window with target 64).
constexpr float LOG2E = 1.4426950408889634f;
constexpr float LN2   = 0.6931471805599453f;

typedef float f32x2 __attribute__((ext_vector_type(2)));

#if __has_builtin(__builtin_amdgcn_exp2f)
__device__ __forceinline__ float fexp2(float x) { return __builtin_amdgcn_exp2f(x); }
#else
__device__ __forceinline__ float fexp2(float x) { return exp2f(x); }
#endif
#if __has_builtin(__builtin_amdgcn_rcpf)
__device__ __forceinline__ float frcp(float x) { return __builtin_amdgcn_rcpf(x); }
#else
__device__ __forceinline__ float frcp(float x) { return 1.0f / x; }
#endif
__device__ __forceinline__ void wavebar() {
#if __has_builtin(__builtin_amdgcn_wave_barrier)
    __builtin_amdgcn_wave_barrier();
#endif
}

// Grid 1024 = 2 blocks per b (32 i-rows each), block 512 (8 waves).
// SINGLE-BARRIER STRUCTURE (r13): r12 ran at ~34us with ~35-40% modeled
// VALUBusy -> latency/barrier slack, not issue saturation. (a) barrier 3
// removed: wave w writes sh rows 4w..4w+3 and its phase-2 threads read only
// those rows - same-wave LDS round-trip (lgkmcnt-ordered). (b) barrier 2
// merged into barrier 1: s computed from GLOBAL concurrently with staging.
// Score loop stays packed-fp32 (r12 win). Gate + phase2 now packed too.
// Gate: __ballot bitmasks (SGPRs). Single-exp identity (exact):
//   elup1(a)*elup1(b) = exp2(min(aL,0)+min(bL,0)) * (1+max(aL,0)*ln2) * (1+max(bL,0)*ln2)
__global__ __launch_bounds__(512, 4) void fused(
        const float* __restrict__ feature,
        const float* __restrict__ ind,
        float* __restrict__ out) {
    __shared__ float ind_lds[3][N][PD];   // 27648 B
    __shared__ float s_lds[3][N];         //   768 B
    __shared__ float sh_lds[32][SHP];     // 13312 B   total 41728 B -> 3 blocks/CU

    const int t      = threadIdx.x;
    const int lane   = t & 63;
    const int wave   = t >> 6;
    const int blk    = blockIdx.x;
    const int b      = blk >> 1;
    const int i_base = (blk & 1) << 5;

    // ---- stage indicator: 1536 float4, 3 per thread, coalesced ----
    {
        const float4* src = reinterpret_cast<const float4*>(ind);
#pragma unroll
        for (int idx = t; idx < 3 * N * D / 4; idx += 512) {
            int a = idx >> 9;
            int r = idx & 511;
            int n = r >> 3;
            int k = r & 7;
            *reinterpret_cast<float4*>(&ind_lds[a][n][k * 4]) = src[idx];
        }
    }

    // ---- s[a][n] = feature[b,n,:] . ind[a,n,:] from GLOBAL, overlapped with
    //      staging (both inputs L2-hot; merges old barrier 2 into barrier 1) ----
    if (t < 3 * N) {
        int a = t >> 6, n = t & 63;
        const float4* frow = reinterpret_cast<const float4*>(feature + ((size_t)b * N + n) * D);
        const float4* irow = reinterpret_cast<const float4*>(ind + (a * N + n) * D);
        f32x2 sa2 = {0.f, 0.f};
#pragma unroll
        for (int k = 0; k < 8; ++k) {
            float4 f4 = frow[k];
            float4 i4 = irow[k];
            sa2 = __builtin_elementwise_fma(f32x2{f4.x, f4.y}, f32x2{i4.x, i4.y}, sa2);
            sa2 = __builtin_elementwise_fma(f32x2{f4.z, f4.w}, f32x2{i4.z, i4.w}, sa2);
        }
        s_lds[a][n] = sa2.x + sa2.y;
    }
    __syncthreads();   // the ONLY block barrier

    // ---- gate bitmasks for this wave's 4 rows (packed fp32, SGPR result) ----
    // gate[ig][lane] = 1[ ind0[ig,:] . ind1[lane,:] > 0 ]
    unsigned long long gmask[4];
    {
        f32x2 ga[4] = {{0.f, 0.f}, {0.f, 0.f}, {0.f, 0.f}, {0.f, 0.f}};
#pragma unroll
        for (int k = 0; k < 8; ++k) {
            float4 w4 = *reinterpret_cast<const float4*>(&ind_lds[1][lane][k * 4]);  // lane read
            f32x2 wp0 = {w4.x, w4.y}, wp1 = {w4.z, w4.w};
#pragma unroll
            for (int r = 0; r < 4; ++r) {
                float4 a4 = *reinterpret_cast<const float4*>(
                    &ind_lds[0][i_base + wave * 4 + r][k * 4]);                      // broadcast
                ga[r] = __builtin_elementwise_fma(f32x2{a4.x, a4.y}, wp0, ga[r]);
                ga[r] = __builtin_elementwise_fma(f32x2{a4.z, a4.w}, wp1, ga[r]);
            }
        }
#pragma unroll
        for (int r = 0; r < 4; ++r) gmask[r] = __ballot(ga[r].x + ga[r].y > 0.f);
    }

    // ---- per-lane: u = ind0[lane,:] in 32 VGPRs (f32x2 pairs); s1 scaled ----
    f32x2 u2[16];
#pragma unroll
    for (int k = 0; k < 8; ++k) {
        float4 v = *reinterpret_cast<const float4*>(&ind_lds[0][lane][k * 4]);
        u2[2 * k + 0] = f32x2{v.x, v.y};
        u2[2 * k + 1] = f32x2{v.z, v.w};
    }
    const float s1Ls = s_lds[1][lane] * LOG2E;
    const f32x2 s1L  = {s1Ls, s1Ls};
    const f32x2 ln2v = {LN2, LN2};
    const f32x2 onev = {1.0f, 1.0f};
    const f32x2 zerv = {0.0f, 0.0f};

    // ---- score: wave rows ig = i_base + wave*4 + r; packed-fp32 inner loop ----
    float score[4];
#pragma unroll
    for (int r = 0; r < 4; ++r) {
        const int   ig   = i_base + wave * 4 + r;
        const float s0Ls = s_lds[0][ig] * LOG2E;
        const f32x2 s0L  = {s0Ls, s0Ls};
        f32x2 sc2 = {0.f, 0.f};
#pragma unroll
        for (int k = 0; k < 8; ++k) {
            float4 v4 = *reinterpret_cast<const float4*>(&ind_lds[1][ig][k * 4]);  // broadcast
            f32x2 vp[2] = {f32x2{v4.x, v4.y}, f32x2{v4.z, v4.w}};
#pragma unroll
            for (int h = 0; h < 2; ++h) {
                f32x2 aL  = s0L * u2[2 * k + h];                       // v_pk_mul
                f32x2 bL  = s1L * vp[h];                               // v_pk_mul
                f32x2 mnS = __builtin_elementwise_min(aL, zerv)
                          + __builtin_elementwise_min(bL, zerv);
                f32x2 E   = {fexp2(mnS.x), fexp2(mnS.y)};              // 2 v_exp
                f32x2 A   = __builtin_elementwise_fma(
                    __builtin_elementwise_max(aL, zerv), ln2v, onev);
                f32x2 Bv  = __builtin_elementwise_fma(
                    __builtin_elementwise_max(bL, zerv), ln2v, onev);
                sc2 = __builtin_elementwise_fma(E * A, Bv, sc2);
            }
        }
        score[r] = sc2.x + sc2.y;
    }

    // ---- 4-way-ILP wave softmax over j (64 lanes) ----
    float mx[4], e[4], sm[4];
#pragma unroll
    for (int r = 0; r < 4; ++r) mx[r] = score[r];
#pragma unroll
    for (int off = 32; off >= 1; off >>= 1) {
#pragma unroll
        for (int r = 0; r < 4; ++r) mx[r] = fmaxf(mx[r], __shfl_xor(mx[r], off));
    }
#pragma unroll
    for (int r = 0; r < 4; ++r) e[r] = fexp2((score[r] - mx[r]) * LOG2E);
#pragma unroll
    for (int r = 0; r < 4; ++r) sm[r] = e[r];
#pragma unroll
    for (int off = 32; off >= 1; off >>= 1) {
#pragma unroll
        for (int r = 0; r < 4; ++r) sm[r] += __shfl_xor(sm[r], off);
    }
#pragma unroll
    for (int r = 0; r < 4; ++r) {
        const int ig    = i_base + wave * 4 + r;
        const int i_loc = wave * 4 + r;
        const float g   = (float)((gmask[r] >> lane) & 1ull);
        sh_lds[i_loc][lane] = (e[r] * g) * (s_lds[2][ig] * frcp(sm[r]));
    }

    // NO block barrier: wave w wrote sh rows 4w..4w+3 and reads only those
    // rows below (same-wave LDS RAW, lgkmcnt-ordered). wave_barrier() pins
    // the instruction order.
    wavebar();

    // ---- phase 2: out[i,:] = sh[i,:] @ ind2; thread = (i_loc, d-quad, j-half);
    //      i_loc = t>>4 spans 4w..4w+3 for wave w (same-wave rows only) ----
    {
        const int i_loc = t >> 4;
        const int sub   = t & 15;
        const int dq    = sub & 7;
        const int jh    = sub >> 3;
        f32x2 acc0 = {0.f, 0.f}, acc1 = {0.f, 0.f};
#pragma unroll
        for (int jj = 0; jj < 32; jj += 4) {
            int j = jh * 32 + jj;
            float4 sh4 = *reinterpret_cast<const float4*>(&sh_lds[i_loc][j]);
#pragma unroll
            for (int c = 0; c < 4; ++c) {
                float4 v4 = *reinterpret_cast<const float4*>(&ind_lds[2][j + c][dq * 4]);
                float  w  = (&sh4.x)[c];
                f32x2 wv = {w, w};
                acc0 = __builtin_elementwise_fma(wv, f32x2{v4.x, v4.y}, acc0);
                acc1 = __builtin_elementwise_fma(wv, f32x2{v4.z, v4.w}, acc1);
            }
        }
        float4 acc = {acc0.x, acc0.y, acc1.x, acc1.y};
        acc.x += __shfl_xor(acc.x, 8);   // combine j-halves (lanes t, t^8)
        acc.y += __shfl_xor(acc.y, 8);
        acc.z += __shfl_xor(acc.z, 8);
        acc.w += __shfl_xor(acc.w, 8);
        if (jh == 0) {
            *reinterpret_cast<float4*>(out + ((size_t)b * N + i_base + i_loc) * D + dq * 4) = acc;
        }
    }
}
}  // namespace

extern "C" void kernel_launch(void* const* d_in, const int* in_sizes, int n_in,
                              void* d_out, int out_size, void* d_ws, size_t ws_size,
                              hipStream_t stream) {
    const float* feature = (const float*)d_in[0];
    const float* ind     = (const float*)d_in[1];
    float*       out     = (float*)d_out;
    fused<<<1024, 512, 0, stream>>>(feature, ind, out);
}

// Round 14
// 80.730 us; speedup vs baseline: 1.3124x; 1.0173x over previous
//
#include <hip/hip_runtime.h>

namespace {
constexpr int N   = 64;
constexpr int D   = 32;
constexpr int PD  = 36;   // padded ind row (dwords): measured conflict-free (r1/r2)
constexpr int SHP = 104;  // sh row pad: >=64 payload (r10 lesson); 104%32==8
                          // conflict-free (r11-r13). LDS 41728 B -> 3-blocks/CU
                          // window -> compiler VGPR target 85 (r4-r6 spill trap
                          // fires in the <=40.96 KB window with target 64).
constexpr float LOG2E = 1.4426950408889634f;
constexpr float LN2   = 0.6931471805599453f;

typedef float f32x2 __attribute__((ext_vector_type(2)));

#if __has_builtin(__builtin_amdgcn_exp2f)
__device__ __forceinline__ float fexp2(float x) { return __builtin_amdgcn_exp2f(x); }
#else
__device__ __forceinline__ float fexp2(float x) { return exp2f(x); }
#endif
#if __has_builtin(__builtin_amdgcn_rcpf)
__device__ __forceinline__ float frcp(float x) { return __builtin_amdgcn_rcpf(x); }
#else
__device__ __forceinline__ float frcp(float x) { return 1.0f / x; }
#endif
__device__ __forceinline__ void wavebar() {
#if __has_builtin(__builtin_amdgcn_wave_barrier)
    __builtin_amdgcn_wave_barrier();
#endif
}

// Grid 1024 = 2 blocks per b (32 i-rows each), block 512 (8 waves).
// r13 base (single block barrier, packed fp32, SGPR gate masks) + r14:
// SIGN-SPLIT SCORE LOOP. s0L is wave-uniform per row, so per-element sign of
// aL = s0L*u is known from sign(u). Precompute un=min(u,0), upl=max(u,0)*ln2
// per 16-float chunk; uniform branch on sign(s0L) (readfirstlane -> s_cbranch,
// zero divergence) selects:
//   s0>=0: a- = s0L*un,          A = fma(s0L, upl, 1)
//   s0<0 : a- = (s0L*log2e)*upl, A = fma(s0L*ln2, un, 1)
// (exact in both paths). Per-pair body: 15+2exp -> 11+2exp issue slots and a
// shorter dep chain into the exp. b-side unchanged (s1L is per-lane).
// Single-exp identity (exact):
//   elup1(a)*elup1(b) = exp2(min(aL,0)+min(bL,0)) * (1+max(aL,0)*ln2) * (1+max(bL,0)*ln2)
__global__ __launch_bounds__(512, 4) void fused(
        const float* __restrict__ feature,
        const float* __restrict__ ind,
        float* __restrict__ out) {
    __shared__ float ind_lds[3][N][PD];   // 27648 B
    __shared__ float s_lds[3][N];         //   768 B
    __shared__ float sh_lds[32][SHP];     // 13312 B   total 41728 B -> 3 blocks/CU

    const int t      = threadIdx.x;
    const int lane   = t & 63;
    const int wave   = t >> 6;
    const int blk    = blockIdx.x;
    const int b      = blk >> 1;
    const int i_base = (blk & 1) << 5;

    // ---- stage indicator: 1536 float4, 3 per thread, coalesced ----
    {
        const float4* src = reinterpret_cast<const float4*>(ind);
#pragma unroll
        for (int idx = t; idx < 3 * N * D / 4; idx += 512) {
            int a = idx >> 9;
            int r = idx & 511;
            int n = r >> 3;
            int k = r & 7;
            *reinterpret_cast<float4*>(&ind_lds[a][n][k * 4]) = src[idx];
        }
    }

    // ---- s[a][n] = feature[b,n,:] . ind[a,n,:] from GLOBAL, overlapped with
    //      staging (merges old barrier 2 into barrier 1; r13-verified) ----
    if (t < 3 * N) {
        int a = t >> 6, n = t & 63;
        const float4* frow = reinterpret_cast<const float4*>(feature + ((size_t)b * N + n) * D);
        const float4* irow = reinterpret_cast<const float4*>(ind + (a * N + n) * D);
        f32x2 sa2 = {0.f, 0.f};
#pragma unroll
        for (int k = 0; k < 8; ++k) {
            float4 f4 = frow[k];
            float4 i4 = irow[k];
            sa2 = __builtin_elementwise_fma(f32x2{f4.x, f4.y}, f32x2{i4.x, i4.y}, sa2);
            sa2 = __builtin_elementwise_fma(f32x2{f4.z, f4.w}, f32x2{i4.z, i4.w}, sa2);
        }
        s_lds[a][n] = sa2.x + sa2.y;
    }
    __syncthreads();   // the ONLY block barrier

    // ---- gate bitmasks for this wave's 4 rows (packed fp32, SGPR result) ----
    unsigned long long gmask[4];
    {
        f32x2 ga[4] = {{0.f, 0.f}, {0.f, 0.f}, {0.f, 0.f}, {0.f, 0.f}};
#pragma unroll
        for (int k = 0; k < 8; ++k) {
            float4 w4 = *reinterpret_cast<const float4*>(&ind_lds[1][lane][k * 4]);  // lane read
            f32x2 wp0 = {w4.x, w4.y}, wp1 = {w4.z, w4.w};
#pragma unroll
            for (int r = 0; r < 4; ++r) {
                float4 a4 = *reinterpret_cast<const float4*>(
                    &ind_lds[0][i_base + wave * 4 + r][k * 4]);                      // broadcast
                ga[r] = __builtin_elementwise_fma(f32x2{a4.x, a4.y}, wp0, ga[r]);
                ga[r] = __builtin_elementwise_fma(f32x2{a4.z, a4.w}, wp1, ga[r]);
            }
        }
#pragma unroll
        for (int r = 0; r < 4; ++r) gmask[r] = __ballot(ga[r].x + ga[r].y > 0.f);
    }

    const float s1Ls = s_lds[1][lane] * LOG2E;
    const f32x2 s1L  = {s1Ls, s1Ls};
    const f32x2 ln2v = {LN2, LN2};
    const f32x2 onev = {1.0f, 1.0f};
    const f32x2 zerv = {0.0f, 0.0f};

    // ---- hoisted row scalars ----
    float s0v[4];
#pragma unroll
    for (int r = 0; r < 4; ++r) s0v[r] = s_lds[0][i_base + wave * 4 + r] * LOG2E;

    // ---- score: sign-split packed loop, 2 chunks of 16 d-elements ----
    f32x2 sc2[4] = {{0.f, 0.f}, {0.f, 0.f}, {0.f, 0.f}, {0.f, 0.f}};

#define SCORE_BODY(NEGA, FMAA, AM, FM)                                              \
    {                                                                               \
        const f32x2 amv = {(AM), (AM)};                                             \
        const f32x2 fmv = {(FM), (FM)};                                             \
        f32x2 acc = sc2[r];                                                         \
        _Pragma("unroll")                                                           \
        for (int k4 = 0; k4 < 4; ++k4) {                                            \
            float4 v4 = *reinterpret_cast<const float4*>(                           \
                &ind_lds[1][ig][c * 16 + k4 * 4]);                                  \
            f32x2 vp[2] = {f32x2{v4.x, v4.y}, f32x2{v4.z, v4.w}};                   \
            _Pragma("unroll")                                                       \
            for (int h = 0; h < 2; ++h) {                                           \
                f32x2 aneg = amv * NEGA[k4 * 2 + h];                                \
                f32x2 A    = __builtin_elementwise_fma(fmv, FMAA[k4 * 2 + h], onev);\
                f32x2 bL   = s1L * vp[h];                                           \
                f32x2 bneg = __builtin_elementwise_min(bL, zerv);                   \
                f32x2 B    = __builtin_elementwise_fma(                             \
                    __builtin_elementwise_max(bL, zerv), ln2v, onev);               \
                f32x2 mn   = aneg + bneg;                                           \
                f32x2 E    = {fexp2(mn.x), fexp2(mn.y)};                            \
                acc = __builtin_elementwise_fma(E * A, B, acc);                     \
            }                                                                       \
        }                                                                           \
        sc2[r] = acc;                                                               \
    }

#pragma unroll
    for (int c = 0; c < 2; ++c) {
        // per-chunk precompute: un = min(u,0), upl = max(u,0)*ln2  (16 f32x2 live)
        f32x2 un[8], upl[8];
#pragma unroll
        for (int k4 = 0; k4 < 4; ++k4) {
            float4 v = *reinterpret_cast<const float4*>(&ind_lds[0][lane][c * 16 + k4 * 4]);
            f32x2 x0 = {v.x, v.y}, x1 = {v.z, v.w};
            f32x2 n0 = __builtin_elementwise_min(x0, zerv);
            f32x2 n1 = __builtin_elementwise_min(x1, zerv);
            un[k4 * 2 + 0]  = n0;
            un[k4 * 2 + 1]  = n1;
            upl[k4 * 2 + 0] = (x0 - n0) * ln2v;
            upl[k4 * 2 + 1] = (x1 - n1) * ln2v;
        }
#pragma unroll
        for (int r = 0; r < 4; ++r) {
            const int ig = i_base + wave * 4 + r;
            // force wave-uniform scalar: s_cmp + s_cbranch, zero divergence
            const float s0u = __uint_as_float(
                __builtin_amdgcn_readfirstlane(__float_as_uint(s0v[r])));
            if (s0u >= 0.f) {
                SCORE_BODY(un, upl, s0u, s0u)
            } else {
                SCORE_BODY(upl, un, s0u * LOG2E, s0u * LN2)
            }
        }
    }
#undef SCORE_BODY

    float score[4];
#pragma unroll
    for (int r = 0; r < 4; ++r) score[r] = sc2[r].x + sc2[r].y;

    // ---- 4-way-ILP wave softmax over j (64 lanes) ----
    float mx[4], e[4], sm[4];
#pragma unroll
    for (int r = 0; r < 4; ++r) mx[r] = score[r];
#pragma unroll
    for (int off = 32; off >= 1; off >>= 1) {
#pragma unroll
        for (int r = 0; r < 4; ++r) mx[r] = fmaxf(mx[r], __shfl_xor(mx[r], off));
    }
#pragma unroll
    for (int r = 0; r < 4; ++r) e[r] = fexp2((score[r] - mx[r]) * LOG2E);
#pragma unroll
    for (int r = 0; r < 4; ++r) sm[r] = e[r];
#pragma unroll
    for (int off = 32; off >= 1; off >>= 1) {
#pragma unroll
        for (int r = 0; r < 4; ++r) sm[r] += __shfl_xor(sm[r], off);
    }
#pragma unroll
    for (int r = 0; r < 4; ++r) {
        const int ig    = i_base + wave * 4 + r;
        const int i_loc = wave * 4 + r;
        const float g   = (float)((gmask[r] >> lane) & 1ull);
        sh_lds[i_loc][lane] = (e[r] * g) * (s_lds[2][ig] * frcp(sm[r]));
    }

    // NO block barrier: wave w wrote sh rows 4w..4w+3 and reads only those
    // rows below (same-wave LDS RAW, lgkmcnt-ordered; r13-verified).
    wavebar();

    // ---- phase 2: out[i,:] = sh[i,:] @ ind2; thread = (i_loc, d-quad, j-half) ----
    {
        const int i_loc = t >> 4;
        const int sub   = t & 15;
        const int dq    = sub & 7;
        const int jh    = sub >> 3;
        f32x2 acc0 = {0.f, 0.f}, acc1 = {0.f, 0.f};
#pragma unroll
        for (int jj = 0; jj < 32; jj += 4) {
            int j = jh * 32 + jj;
            float4 sh4 = *reinterpret_cast<const float4*>(&sh_lds[i_loc][j]);
#pragma unroll
            for (int c = 0; c < 4; ++c) {
                float4 v4 = *reinterpret_cast<const float4*>(&ind_lds[2][j + c][dq * 4]);
                float  w  = (&sh4.x)[c];
                f32x2 wv = {w, w};
                acc0 = __builtin_elementwise_fma(wv, f32x2{v4.x, v4.y}, acc0);
                acc1 = __builtin_elementwise_fma(wv, f32x2{v4.z, v4.w}, acc1);
            }
        }
        float4 acc = {acc0.x, acc0.y, acc1.x, acc1.y};
        acc.x += __shfl_xor(acc.x, 8);   // combine j-halves (lanes t, t^8)
        acc.y += __shfl_xor(acc.y, 8);
        acc.z += __shfl_xor(acc.z, 8);
        acc.w += __shfl_xor(acc.w, 8);
        if (jh == 0) {
            *reinterpret_cast<float4*>(out + ((size_t)b * N + i_base + i_loc) * D + dq * 4) = acc;
        }
    }
}
}  // namespace

extern "C" void kernel_launch(void* const* d_in, const int* in_sizes, int n_in,
                              void* d_out, int out_size, void* d_ws, size_t ws_size,
                              hipStream_t stream) {
    const float* feature = (const float*)d_in[0];
    const float* ind     = (const float*)d_in[1];
    float*       out     = (float*)d_out;
    fused<<<1024, 512, 0, stream>>>(feature, ind, out);
}